// Round 1
// baseline (2210.822 us; speedup 1.0000x reference)
//
#include <hip/hip_runtime.h>
#include <stdint.h>

#define BATCH 4096
#define IN    2048
#define HID   8192
#define NCLS  1000

#define BM 64
#define BN 64
#define BK 32

// Monotonic float->uint key: larger float => larger key.
__device__ __forceinline__ unsigned int fkey(float f) {
    unsigned int u = __float_as_uint(f);
    return (u & 0x80000000u) ? ~u : (u | 0x80000000u);
}

__global__ void init_ws_kernel(unsigned long long* rowkey) {
    int i = blockIdx.x * blockDim.x + threadIdx.x;
    if (i < BATCH) rowkey[i] = 0ULL;
}

// C[m,n] = sum_k x[m,k] * Wk[n,k]; fused per-row argmax via packed u64 atomicMax.
// Normalization of x is skipped: argmax is invariant under positive row scaling.
__global__ __launch_bounds__(256) void gemm_argmax_kernel(
    const float* __restrict__ x, const float* __restrict__ Wk,
    unsigned long long* __restrict__ rowkey)
{
    __shared__ __align__(16) float As[BK * BM];  // transposed: As[k][m]
    __shared__ __align__(16) float Bs[BK * BN];  // transposed: Bs[k][n]

    const int tid = threadIdx.x;
    const int bm = blockIdx.y * BM;
    const int bn = blockIdx.x * BN;

    const int tx = tid & 15;   // column group 0..15
    const int ty = tid >> 4;   // row group 0..15

    float acc[4][4];
    #pragma unroll
    for (int i = 0; i < 4; i++)
        #pragma unroll
        for (int j = 0; j < 4; j++) acc[i][j] = 0.f;

    // Staging: 512 float4 per tile per matrix; 2 per thread per matrix.
    const int r0 = tid >> 3,         q0 = tid & 7;          // rows 0..31
    const int r1 = (tid + 256) >> 3, q1 = (tid + 256) & 7;  // rows 32..63

    const float* xA0 = &x[(size_t)(bm + r0) * IN + q0 * 4];
    const float* xA1 = &x[(size_t)(bm + r1) * IN + q1 * 4];
    const float* wB0 = &Wk[(size_t)(bn + r0) * IN + q0 * 4];
    const float* wB1 = &Wk[(size_t)(bn + r1) * IN + q1 * 4];

    for (int k0 = 0; k0 < IN; k0 += BK) {
        float4 a0 = *(const float4*)(xA0 + k0);
        float4 a1 = *(const float4*)(xA1 + k0);
        float4 b0 = *(const float4*)(wB0 + k0);
        float4 b1 = *(const float4*)(wB1 + k0);

        __syncthreads();  // previous iteration's reads must be done

        As[(q0 * 4 + 0) * BM + r0] = a0.x;
        As[(q0 * 4 + 1) * BM + r0] = a0.y;
        As[(q0 * 4 + 2) * BM + r0] = a0.z;
        As[(q0 * 4 + 3) * BM + r0] = a0.w;
        As[(q1 * 4 + 0) * BM + r1] = a1.x;
        As[(q1 * 4 + 1) * BM + r1] = a1.y;
        As[(q1 * 4 + 2) * BM + r1] = a1.z;
        As[(q1 * 4 + 3) * BM + r1] = a1.w;

        Bs[(q0 * 4 + 0) * BN + r0] = b0.x;
        Bs[(q0 * 4 + 1) * BN + r0] = b0.y;
        Bs[(q0 * 4 + 2) * BN + r0] = b0.z;
        Bs[(q0 * 4 + 3) * BN + r0] = b0.w;
        Bs[(q1 * 4 + 0) * BN + r1] = b1.x;
        Bs[(q1 * 4 + 1) * BN + r1] = b1.y;
        Bs[(q1 * 4 + 2) * BN + r1] = b1.z;
        Bs[(q1 * 4 + 3) * BN + r1] = b1.w;

        __syncthreads();

        #pragma unroll
        for (int k = 0; k < BK; k++) {
            float4 av = *(const float4*)&As[k * BM + ty * 4];
            float4 bv = *(const float4*)&Bs[k * BN + tx * 4];
            acc[0][0] += av.x * bv.x; acc[0][1] += av.x * bv.y;
            acc[0][2] += av.x * bv.z; acc[0][3] += av.x * bv.w;
            acc[1][0] += av.y * bv.x; acc[1][1] += av.y * bv.y;
            acc[1][2] += av.y * bv.z; acc[1][3] += av.y * bv.w;
            acc[2][0] += av.z * bv.x; acc[2][1] += av.z * bv.y;
            acc[2][2] += av.z * bv.z; acc[2][3] += av.z * bv.w;
            acc[3][0] += av.w * bv.x; acc[3][1] += av.w * bv.y;
            acc[3][2] += av.w * bv.z; acc[3][3] += av.w * bv.w;
        }
    }

    // Epilogue: per-row argmax. Each row of the 64-row tile is owned by the
    // 16 lanes (same ty) of one wave; xor-shuffle reduce then one atomic.
    #pragma unroll
    for (int i = 0; i < 4; i++) {
        const int row = bm + ty * 4 + i;
        unsigned long long best = 0ULL;
        #pragma unroll
        for (int j = 0; j < 4; j++) {
            const int col = bn + tx * 4 + j;
            unsigned long long p =
                ((unsigned long long)fkey(acc[i][j]) << 32) |
                (unsigned long long)(0x1FFFu - (unsigned)col);  // smaller col wins ties
            if (p > best) best = p;
        }
        #pragma unroll
        for (int off = 1; off < 16; off <<= 1) {
            unsigned long long other = __shfl_xor(best, off, 64);
            if (other > best) best = other;
        }
        if (tx == 0) atomicMax(&rowkey[row], best);
    }
}

// out[b, c] = Wg[c, idx[b]]
__global__ __launch_bounds__(256) void gather_kernel(
    const unsigned long long* __restrict__ rowkey,
    const float* __restrict__ Wg, float* __restrict__ out)
{
    const int b = blockIdx.y;
    const int c = blockIdx.x * blockDim.x + threadIdx.x;
    if (c >= NCLS) return;
    const int col = 0x1FFF - (int)(rowkey[b] & 0xFFFFFFFFu);
    out[(size_t)b * NCLS + c] = Wg[(size_t)c * HID + col];
}

extern "C" void kernel_launch(void* const* d_in, const int* in_sizes, int n_in,
                              void* d_out, int out_size, void* d_ws, size_t ws_size,
                              hipStream_t stream) {
    const float* x  = (const float*)d_in[0];   // [BATCH, IN]
    const float* Wk = (const float*)d_in[1];   // [HID, IN]
    const float* Wg = (const float*)d_in[2];   // [NCLS, HID]
    float* out = (float*)d_out;                // [BATCH, NCLS]
    unsigned long long* rowkey = (unsigned long long*)d_ws;  // [BATCH]

    hipLaunchKernelGGL(init_ws_kernel, dim3((BATCH + 255) / 256), dim3(256), 0, stream,
                       rowkey);
    hipLaunchKernelGGL(gemm_argmax_kernel, dim3(HID / BN, BATCH / BM), dim3(256), 0, stream,
                       x, Wk, rowkey);
    hipLaunchKernelGGL(gather_kernel, dim3((NCLS + 255) / 256, BATCH), dim3(256), 0, stream,
                       rowkey, Wg, out);
}

// Round 2
// 402.018 us; speedup vs baseline: 5.4993x; 5.4993x over previous
//
#include <hip/hip_runtime.h>
#include <stdint.h>

typedef unsigned int u32;
typedef unsigned long long u64;
typedef unsigned short u16;
typedef short short8 __attribute__((ext_vector_type(8)));
typedef float floatx4 __attribute__((ext_vector_type(4)));

#define BATCH 4096
#define IN    2048
#define HID   8192
#define NCLS  1000

// ---------- ws layout ----------
#define OFF_ROWKEY 0u                      // u64[4096]   32 KB
#define OFF_ROWMAX 32768u                  // u32[4096]   16 KB
#define OFF_XB     49152u                  // bf16 x      16 MB
#define OFF_WKB    16826368u               // bf16 Wk     32 MB
#define OFF_S      50380800u               // bf16 S      64 MB
#define OFF_WGT    117489664u              // fp32 Wg^T   31.25 MB
#define TOTAL_NOWGT 117489664ull
#define TOTAL_FULL  150257664ull

// ---------- helpers ----------
__device__ __forceinline__ u32 f2bf(float f) {          // fp32 -> bf16 bits (RNE)
    u32 u = __float_as_uint(f);
    return (u + 0x7FFFu + ((u >> 16) & 1u)) >> 16;
}
__device__ __forceinline__ float bf2f(u32 b) { return __uint_as_float(b << 16); }
__device__ __forceinline__ u32 fkey(float f) {          // monotonic float->u32
    u32 u = __float_as_uint(f);
    return (u & 0x80000000u) ? ~u : (u | 0x80000000u);
}
__device__ __forceinline__ float unfkey(u32 k) {
    return __uint_as_float((k & 0x80000000u) ? (k ^ 0x80000000u) : ~k);
}

// ---------- prep: zero keys, convert x & Wk to bf16 ----------
__global__ __launch_bounds__(256) void prep_kernel(
    const float* __restrict__ x, const float* __restrict__ Wk,
    u32* __restrict__ xb, u32* __restrict__ wkb,
    u32* __restrict__ rowmax, u64* __restrict__ rowkey)
{
    const int gid = blockIdx.x * 256 + threadIdx.x;
    if (gid < BATCH) { rowmax[gid] = 0u; rowkey[gid] = 0ull; }
    const int NSEG_X = BATCH * IN / 8;   // 8-float segments
    const int NSEG_W = HID * IN / 8;
    const int stride = gridDim.x * 256;
    for (int s = gid; s < NSEG_X + NSEG_W; s += stride) {
        const float* src;
        u32* dst;
        if (s < NSEG_X) { src = x + (size_t)s * 8;            dst = xb  + (size_t)s * 4; }
        else { int t = s - NSEG_X; src = Wk + (size_t)t * 8;  dst = wkb + (size_t)t * 4; }
        float4 a = ((const float4*)src)[0];
        float4 b = ((const float4*)src)[1];
        uint4 o;
        o.x = f2bf(a.x) | (f2bf(a.y) << 16);
        o.y = f2bf(a.z) | (f2bf(a.w) << 16);
        o.z = f2bf(b.x) | (f2bf(b.y) << 16);
        o.w = f2bf(b.z) | (f2bf(b.w) << 16);
        ((uint4*)dst)[0] = o;
    }
}

// ---------- Wg transpose for coalesced gather ----------
__global__ __launch_bounds__(256) void transpose_wg_kernel(
    const float* __restrict__ Wg, float* __restrict__ WgT)
{
    __shared__ float t[32][33];
    const int bx = blockIdx.x * 32;  // HID
    const int by = blockIdx.y * 32;  // NCLS
    const int tx = threadIdx.x & 31, ty = threadIdx.x >> 5;  // ty 0..7
    #pragma unroll
    for (int i = 0; i < 32; i += 8) {
        int c = by + ty + i;
        t[ty + i][tx] = (c < NCLS) ? Wg[(size_t)c * HID + bx + tx] : 0.f;
    }
    __syncthreads();
    #pragma unroll
    for (int i = 0; i < 32; i += 8) {
        int c = by + tx;
        if (c < NCLS) WgT[(size_t)(bx + ty + i) * NCLS + by + tx] = t[tx][ty + i];
    }
}

// ---------- bf16 MFMA GEMM: S~[b][h] + per-row approx max ----------
// 128x128 tile, BK=32, 4 waves, each wave owns a 64x64 quadrant (4x4 MFMA tiles)
__global__ __launch_bounds__(256) void mfma_gemm_kernel(
    const u16* __restrict__ xb, const u16* __restrict__ wkb,
    u16* __restrict__ S, u32* __restrict__ rowmax)
{
    __shared__ u16 At[128 * 32];   // [row][k], rows of x      (8 KB)
    __shared__ u16 Bt[128 * 32];   // [row][k], rows of Wk     (8 KB)

    const int tid  = threadIdx.x;
    const int lane = tid & 63;
    const int w    = tid >> 6;
    const int bm   = blockIdx.y * 128;
    const int bn   = blockIdx.x * 128;
    const int wrow = (w >> 1) * 64, wcol = (w & 1) * 64;
    const int m = lane & 15, q = lane >> 4;

    floatx4 acc[4][4];
    #pragma unroll
    for (int i = 0; i < 4; i++)
        #pragma unroll
        for (int j = 0; j < 4; j++)
            acc[i][j] = (floatx4){0.f, 0.f, 0.f, 0.f};

    // staging: segment s in {tid, tid+256}; row = s>>2, k8 = s&3; LDS granule = s
    const int row0 = tid >> 2, k8_0 = tid & 3;
    const int row1 = (tid + 256) >> 2, k8_1 = (tid + 256) & 3;
    const u16* gxa0 = xb  + (size_t)(bm + row0) * IN + k8_0 * 8;
    const u16* gxa1 = xb  + (size_t)(bm + row1) * IN + k8_1 * 8;
    const u16* gwb0 = wkb + (size_t)(bn + row0) * IN + k8_0 * 8;
    const u16* gwb1 = wkb + (size_t)(bn + row1) * IN + k8_1 * 8;

    for (int k0 = 0; k0 < IN; k0 += 32) {
        __builtin_amdgcn_global_load_lds(
            (const __attribute__((address_space(1))) u32*)(gxa0 + k0),
            (__attribute__((address_space(3))) u32*)&At[tid * 8], 16, 0, 0);
        __builtin_amdgcn_global_load_lds(
            (const __attribute__((address_space(1))) u32*)(gxa1 + k0),
            (__attribute__((address_space(3))) u32*)&At[(tid + 256) * 8], 16, 0, 0);
        __builtin_amdgcn_global_load_lds(
            (const __attribute__((address_space(1))) u32*)(gwb0 + k0),
            (__attribute__((address_space(3))) u32*)&Bt[tid * 8], 16, 0, 0);
        __builtin_amdgcn_global_load_lds(
            (const __attribute__((address_space(1))) u32*)(gwb1 + k0),
            (__attribute__((address_space(3))) u32*)&Bt[(tid + 256) * 8], 16, 0, 0);

        __syncthreads();   // drains vmcnt(0): staging complete for all waves

        short8 af[4], bfr[4];
        #pragma unroll
        for (int i = 0; i < 4; i++) {
            af[i]  = *(const short8*)&At[(wrow + i * 16 + m) * 32 + q * 8];
            bfr[i] = *(const short8*)&Bt[(wcol + i * 16 + m) * 32 + q * 8];
        }
        #pragma unroll
        for (int i = 0; i < 4; i++)
            #pragma unroll
            for (int j = 0; j < 4; j++)
                acc[i][j] = __builtin_amdgcn_mfma_f32_16x16x32_bf16(
                    af[i], bfr[j], acc[i][j], 0, 0, 0);

        __syncthreads();   // all reads done before next overwrite
    }

    // epilogue: store bf16 scores, per-row max via 16-lane shuffle + atomic
    #pragma unroll
    for (int i = 0; i < 4; i++) {
        #pragma unroll
        for (int r = 0; r < 4; r++) {
            const int grow = bm + wrow + i * 16 + q * 4 + r;
            float best = -3.4e38f;
            #pragma unroll
            for (int j = 0; j < 4; j++) {
                const int gcol = bn + wcol + j * 16 + m;
                u32 b = f2bf(acc[i][j][r]);
                S[(size_t)grow * HID + gcol] = (u16)b;
                float vb = bf2f(b);
                if (vb > best) best = vb;
            }
            u32 key = fkey(best);
            #pragma unroll
            for (int off = 1; off < 16; off <<= 1) {
                u32 o = __shfl_xor(key, off, 64);
                if (o > key) key = o;
            }
            if (m == 0) atomicMax(&rowmax[grow], key);
        }
    }
}

// ---------- scan row for candidates near approx max, exact fp32 rescore ----------
__global__ __launch_bounds__(256) void scan_kernel(
    const u16* __restrict__ S, const u32* __restrict__ rowmax,
    const float* __restrict__ x, const float* __restrict__ Wk,
    u64* __restrict__ rowkey)
{
    __shared__ int cnt;
    __shared__ int cand[64];
    __shared__ float wpart[4];
    const int row = blockIdx.x;
    const int tid = threadIdx.x;
    if (tid == 0) cnt = 0;
    __syncthreads();

    const float thr = unfkey(rowmax[row]) - 1.5f;
    const uint4* Sr = (const uint4*)(S + (size_t)row * HID);   // 1024 uint4/row
    #pragma unroll
    for (int t = 0; t < 4; t++) {
        const int seg = tid + t * 256;
        uint4 v = Sr[seg];
        const int base = seg * 8;
        u32 p[4] = {v.x, v.y, v.z, v.w};
        #pragma unroll
        for (int e = 0; e < 4; e++) {
            float f0 = bf2f(p[e] & 0xFFFFu);
            float f1 = __uint_as_float(p[e] & 0xFFFF0000u);
            if (f0 >= thr) { int c = atomicAdd(&cnt, 1); if (c < 64) cand[c] = base + e * 2; }
            if (f1 >= thr) { int c = atomicAdd(&cnt, 1); if (c < 64) cand[c] = base + e * 2 + 1; }
        }
    }
    __syncthreads();
    const int n = min(cnt, 64);

    if (n == 1) {   // unambiguous winner, no rescore needed
        if (tid == 0) rowkey[row] = (0xFFFFFFFFull << 32) | (u64)(0x1FFFu - (u32)cand[0]);
        return;
    }

    u64 best = 0ull;
    const float4* xr = (const float4*)(x + (size_t)row * IN);
    for (int c = 0; c < n; c++) {
        const int h = cand[c];
        const float4* wr = (const float4*)(Wk + (size_t)h * IN);
        float4 a0 = xr[tid * 2], a1 = xr[tid * 2 + 1];
        float4 b0 = wr[tid * 2], b1 = wr[tid * 2 + 1];
        float p = a0.x * b0.x + a0.y * b0.y + a0.z * b0.z + a0.w * b0.w
                + a1.x * b1.x + a1.y * b1.y + a1.z * b1.z + a1.w * b1.w;
        #pragma unroll
        for (int off = 1; off < 64; off <<= 1) p += __shfl_xor(p, off, 64);
        if ((tid & 63) == 0) wpart[tid >> 6] = p;
        __syncthreads();
        if (tid == 0) {
            float s = wpart[0] + wpart[1] + wpart[2] + wpart[3];
            u64 key = ((u64)fkey(s) << 32) | (u64)(0x1FFFu - (u32)h);
            if (key > best) best = key;
        }
        __syncthreads();
    }
    if (tid == 0) rowkey[row] = best;
}

// ---------- gathers ----------
__global__ __launch_bounds__(256) void gatherT_kernel(
    const u64* __restrict__ rowkey, const float* __restrict__ WgT,
    float* __restrict__ out)
{
    const int b = blockIdx.y;
    const int c = blockIdx.x * 256 + threadIdx.x;
    if (c >= NCLS) return;
    const int col = 0x1FFF - (int)(rowkey[b] & 0xFFFFFFFFu);
    out[(size_t)b * NCLS + c] = WgT[(size_t)col * NCLS + c];
}

__global__ __launch_bounds__(256) void gather_kernel(
    const u64* __restrict__ rowkey, const float* __restrict__ Wg,
    float* __restrict__ out)
{
    const int b = blockIdx.y;
    const int c = blockIdx.x * 256 + threadIdx.x;
    if (c >= NCLS) return;
    const int col = 0x1FFF - (int)(rowkey[b] & 0xFFFFFFFFu);
    out[(size_t)b * NCLS + c] = Wg[(size_t)c * HID + col];
}

// ---------- round-1 fp32 fallback (used only if ws too small) ----------
__global__ void init_ws_kernel(u64* rowkey) {
    int i = blockIdx.x * blockDim.x + threadIdx.x;
    if (i < BATCH) rowkey[i] = 0ULL;
}

__global__ __launch_bounds__(256) void gemm_argmax_kernel(
    const float* __restrict__ x, const float* __restrict__ Wk,
    u64* __restrict__ rowkey)
{
    __shared__ __align__(16) float As[32 * 64];
    __shared__ __align__(16) float Bs[32 * 64];
    const int tid = threadIdx.x;
    const int bm = blockIdx.y * 64, bn = blockIdx.x * 64;
    const int tx = tid & 15, ty = tid >> 4;
    float acc[4][4];
    #pragma unroll
    for (int i = 0; i < 4; i++)
        #pragma unroll
        for (int j = 0; j < 4; j++) acc[i][j] = 0.f;
    const int r0 = tid >> 3, q0 = tid & 7;
    const int r1 = (tid + 256) >> 3, q1 = (tid + 256) & 7;
    const float* xA0 = &x[(size_t)(bm + r0) * IN + q0 * 4];
    const float* xA1 = &x[(size_t)(bm + r1) * IN + q1 * 4];
    const float* wB0 = &Wk[(size_t)(bn + r0) * IN + q0 * 4];
    const float* wB1 = &Wk[(size_t)(bn + r1) * IN + q1 * 4];
    for (int k0 = 0; k0 < IN; k0 += 32) {
        float4 a0 = *(const float4*)(xA0 + k0);
        float4 a1 = *(const float4*)(xA1 + k0);
        float4 b0 = *(const float4*)(wB0 + k0);
        float4 b1 = *(const float4*)(wB1 + k0);
        __syncthreads();
        As[(q0 * 4 + 0) * 64 + r0] = a0.x; As[(q0 * 4 + 1) * 64 + r0] = a0.y;
        As[(q0 * 4 + 2) * 64 + r0] = a0.z; As[(q0 * 4 + 3) * 64 + r0] = a0.w;
        As[(q1 * 4 + 0) * 64 + r1] = a1.x; As[(q1 * 4 + 1) * 64 + r1] = a1.y;
        As[(q1 * 4 + 2) * 64 + r1] = a1.z; As[(q1 * 4 + 3) * 64 + r1] = a1.w;
        Bs[(q0 * 4 + 0) * 64 + r0] = b0.x; Bs[(q0 * 4 + 1) * 64 + r0] = b0.y;
        Bs[(q0 * 4 + 2) * 64 + r0] = b0.z; Bs[(q0 * 4 + 3) * 64 + r0] = b0.w;
        Bs[(q1 * 4 + 0) * 64 + r1] = b1.x; Bs[(q1 * 4 + 1) * 64 + r1] = b1.y;
        Bs[(q1 * 4 + 2) * 64 + r1] = b1.z; Bs[(q1 * 4 + 3) * 64 + r1] = b1.w;
        __syncthreads();
        #pragma unroll
        for (int k = 0; k < 32; k++) {
            float4 av = *(const float4*)&As[k * 64 + ty * 4];
            float4 bv = *(const float4*)&Bs[k * 64 + tx * 4];
            acc[0][0] += av.x * bv.x; acc[0][1] += av.x * bv.y;
            acc[0][2] += av.x * bv.z; acc[0][3] += av.x * bv.w;
            acc[1][0] += av.y * bv.x; acc[1][1] += av.y * bv.y;
            acc[1][2] += av.y * bv.z; acc[1][3] += av.y * bv.w;
            acc[2][0] += av.z * bv.x; acc[2][1] += av.z * bv.y;
            acc[2][2] += av.z * bv.z; acc[2][3] += av.z * bv.w;
            acc[3][0] += av.w * bv.x; acc[3][1] += av.w * bv.y;
            acc[3][2] += av.w * bv.z; acc[3][3] += av.w * bv.w;
        }
    }
    #pragma unroll
    for (int i = 0; i < 4; i++) {
        const int row = bm + ty * 4 + i;
        u64 best = 0ULL;
        #pragma unroll
        for (int j = 0; j < 4; j++) {
            const int col = bn + tx * 4 + j;
            u64 p = ((u64)fkey(acc[i][j]) << 32) | (u64)(0x1FFFu - (unsigned)col);
            if (p > best) best = p;
        }
        #pragma unroll
        for (int off = 1; off < 16; off <<= 1) {
            u64 other = __shfl_xor(best, off, 64);
            if (other > best) best = other;
        }
        if (tx == 0) atomicMax(&rowkey[row], best);
    }
}

// ---------- launch ----------
extern "C" void kernel_launch(void* const* d_in, const int* in_sizes, int n_in,
                              void* d_out, int out_size, void* d_ws, size_t ws_size,
                              hipStream_t stream) {
    const float* x  = (const float*)d_in[0];
    const float* Wk = (const float*)d_in[1];
    const float* Wg = (const float*)d_in[2];
    float* out = (float*)d_out;
    char* ws = (char*)d_ws;

    u64* rowkey = (u64*)(ws + OFF_ROWKEY);

    if (ws_size >= TOTAL_NOWGT) {
        u32* rowmax = (u32*)(ws + OFF_ROWMAX);
        u32* xb     = (u32*)(ws + OFF_XB);
        u32* wkb    = (u32*)(ws + OFF_WKB);
        u16* Smat   = (u16*)(ws + OFF_S);
        const bool useT = ws_size >= TOTAL_FULL;
        float* WgT  = (float*)(ws + OFF_WGT);

        hipLaunchKernelGGL(prep_kernel, dim3(2048), dim3(256), 0, stream,
                           x, Wk, xb, wkb, rowmax, rowkey);
        if (useT)
            hipLaunchKernelGGL(transpose_wg_kernel, dim3(256, 32), dim3(256), 0, stream,
                               Wg, WgT);
        hipLaunchKernelGGL(mfma_gemm_kernel, dim3(HID / 128, BATCH / 128), dim3(256), 0, stream,
                           (const u16*)xb, (const u16*)wkb, Smat, rowmax);
        hipLaunchKernelGGL(scan_kernel, dim3(BATCH), dim3(256), 0, stream,
                           Smat, rowmax, x, Wk, rowkey);
        if (useT)
            hipLaunchKernelGGL(gatherT_kernel, dim3(4, BATCH), dim3(256), 0, stream,
                               rowkey, WgT, out);
        else
            hipLaunchKernelGGL(gather_kernel, dim3(4, BATCH), dim3(256), 0, stream,
                               rowkey, Wg, out);
    } else {
        hipLaunchKernelGGL(init_ws_kernel, dim3(16), dim3(256), 0, stream, rowkey);
        hipLaunchKernelGGL(gemm_argmax_kernel, dim3(HID / 64, BATCH / 64), dim3(256), 0, stream,
                           x, Wk, rowkey);
        hipLaunchKernelGGL(gather_kernel, dim3(4, BATCH), dim3(256), 0, stream,
                           rowkey, Wg, out);
    }
}

// Round 3
// 350.520 us; speedup vs baseline: 6.3073x; 1.1469x over previous
//
#include <hip/hip_runtime.h>
#include <stdint.h>

typedef unsigned int u32;
typedef unsigned long long u64;
typedef unsigned short u16;
typedef short short8 __attribute__((ext_vector_type(8)));
typedef float floatx4 __attribute__((ext_vector_type(4)));

#define BATCH 4096
#define IN    2048
#define HID   8192
#define NCLS  1000

// ---------- ws layout (bytes) ----------
#define OFF_ROWKEY 0u                       // u64[4096]        32 KB (fallback path)
#define OFF_TOPK   32768u                   // u64[4096*256]     8 MB
#define OFF_XB     8421376u                 // bf16 x           16 MB
#define OFF_WKB    25198592u                // bf16 Wk          32 MB
#define OFF_WGT    58753024u                // fp32 Wg^T     31.25 MB
#define TOTAL_FULL 91521024ull

// ---------- helpers ----------
__device__ __forceinline__ u32 f2bf(float f) {          // fp32 -> bf16 bits (RNE)
    u32 u = __float_as_uint(f);
    return (u + 0x7FFFu + ((u >> 16) & 1u)) >> 16;
}
__device__ __forceinline__ u32 fkey(float f) {          // monotonic float->u32
    u32 u = __float_as_uint(f);
    return (u & 0x80000000u) ? ~u : (u | 0x80000000u);
}
__device__ __forceinline__ float unfkey(u32 k) {
    return __uint_as_float((k & 0x80000000u) ? (k ^ 0x80000000u) : ~k);
}

// ---------- prep: convert x & Wk to bf16 ----------
__global__ __launch_bounds__(256) void prep_kernel(
    const float* __restrict__ x, const float* __restrict__ Wk,
    u32* __restrict__ xb, u32* __restrict__ wkb)
{
    const int gid = blockIdx.x * 256 + threadIdx.x;
    const int NSEG_X = BATCH * IN / 8;   // 8-float segments
    const int NSEG_W = HID * IN / 8;
    const int stride = gridDim.x * 256;
    for (int s = gid; s < NSEG_X + NSEG_W; s += stride) {
        const float* src;
        u32* dst;
        if (s < NSEG_X) { src = x + (size_t)s * 8;            dst = xb  + (size_t)s * 4; }
        else { int t = s - NSEG_X; src = Wk + (size_t)t * 8;  dst = wkb + (size_t)t * 4; }
        float4 a = ((const float4*)src)[0];
        float4 b = ((const float4*)src)[1];
        uint4 o;
        o.x = f2bf(a.x) | (f2bf(a.y) << 16);
        o.y = f2bf(a.z) | (f2bf(a.w) << 16);
        o.z = f2bf(b.x) | (f2bf(b.y) << 16);
        o.w = f2bf(b.z) | (f2bf(b.w) << 16);
        ((uint4*)dst)[0] = o;
    }
}

// ---------- Wg transpose for coalesced gather ----------
__global__ __launch_bounds__(256) void transpose_wg_kernel(
    const float* __restrict__ Wg, float* __restrict__ WgT)
{
    __shared__ float t[32][33];
    const int bx = blockIdx.x * 32;  // HID
    const int by = blockIdx.y * 32;  // NCLS
    const int tx = threadIdx.x & 31, ty = threadIdx.x >> 5;  // ty 0..7
    #pragma unroll
    for (int i = 0; i < 32; i += 8) {
        int c = by + ty + i;
        t[ty + i][tx] = (c < NCLS) ? Wg[(size_t)c * HID + bx + tx] : 0.f;
    }
    __syncthreads();
    #pragma unroll
    for (int i = 0; i < 32; i += 8) {
        int c = by + tx;
        if (c < NCLS) WgT[(size_t)(bx + ty + i) * NCLS + by + tx] = t[tx][ty + i];
    }
}

// ---------- bf16 MFMA GEMM: per-(row, 64-col-group) top-2 keys ----------
// 128x128 tile, BK=32, 4 waves, each wave owns a 64x64 quadrant (4x4 MFMA tiles)
__global__ __launch_bounds__(256) void mfma_gemm_kernel(
    const u16* __restrict__ xb, const u16* __restrict__ wkb,
    u64* __restrict__ topk)
{
    __shared__ u16 At[128 * 32];   // [row][k], rows of x      (8 KB)
    __shared__ u16 Bt[128 * 32];   // [row][k], rows of Wk     (8 KB)

    const int tid  = threadIdx.x;
    const int lane = tid & 63;
    const int w    = tid >> 6;
    const int bm   = blockIdx.y * 128;
    const int bn   = blockIdx.x * 128;
    const int wrow = (w >> 1) * 64, wcol = (w & 1) * 64;
    const int m = lane & 15, q = lane >> 4;

    floatx4 acc[4][4];
    #pragma unroll
    for (int i = 0; i < 4; i++)
        #pragma unroll
        for (int j = 0; j < 4; j++)
            acc[i][j] = (floatx4){0.f, 0.f, 0.f, 0.f};

    // staging: segment s in {tid, tid+256}; row = s>>2, k8 = s&3
    const int row0 = tid >> 2, k8_0 = tid & 3;
    const int row1 = (tid + 256) >> 2, k8_1 = (tid + 256) & 3;
    const u16* gxa0 = xb  + (size_t)(bm + row0) * IN + k8_0 * 8;
    const u16* gxa1 = xb  + (size_t)(bm + row1) * IN + k8_1 * 8;
    const u16* gwb0 = wkb + (size_t)(bn + row0) * IN + k8_0 * 8;
    const u16* gwb1 = wkb + (size_t)(bn + row1) * IN + k8_1 * 8;

    for (int k0 = 0; k0 < IN; k0 += 32) {
        __builtin_amdgcn_global_load_lds(
            (const __attribute__((address_space(1))) u32*)(gxa0 + k0),
            (__attribute__((address_space(3))) u32*)&At[tid * 8], 16, 0, 0);
        __builtin_amdgcn_global_load_lds(
            (const __attribute__((address_space(1))) u32*)(gxa1 + k0),
            (__attribute__((address_space(3))) u32*)&At[(tid + 256) * 8], 16, 0, 0);
        __builtin_amdgcn_global_load_lds(
            (const __attribute__((address_space(1))) u32*)(gwb0 + k0),
            (__attribute__((address_space(3))) u32*)&Bt[tid * 8], 16, 0, 0);
        __builtin_amdgcn_global_load_lds(
            (const __attribute__((address_space(1))) u32*)(gwb1 + k0),
            (__attribute__((address_space(3))) u32*)&Bt[(tid + 256) * 8], 16, 0, 0);

        __syncthreads();   // drains vmcnt(0): staging complete for all waves

        short8 af[4], bfr[4];
        #pragma unroll
        for (int i = 0; i < 4; i++) {
            af[i]  = *(const short8*)&At[(wrow + i * 16 + m) * 32 + q * 8];
            bfr[i] = *(const short8*)&Bt[(wcol + i * 16 + m) * 32 + q * 8];
        }
        #pragma unroll
        for (int i = 0; i < 4; i++)
            #pragma unroll
            for (int j = 0; j < 4; j++)
                acc[i][j] = __builtin_amdgcn_mfma_f32_16x16x32_bf16(
                    af[i], bfr[j], acc[i][j], 0, 0, 0);

        __syncthreads();   // all reads done before next overwrite
    }

    // epilogue: per-row top-2 over this wave's 64 columns.
    // Row grow is shared by the 16 lanes with equal q; butterfly over m.
    const int g = blockIdx.x * 2 + (wcol >> 6);   // 64-col group id, 0..127
    #pragma unroll
    for (int i = 0; i < 4; i++) {
        #pragma unroll
        for (int r = 0; r < 4; r++) {
            const int grow = bm + wrow + i * 16 + q * 4 + r;
            u64 b = 0ull, s = 0ull;
            #pragma unroll
            for (int j = 0; j < 4; j++) {
                const int gcol = bn + wcol + j * 16 + m;
                u64 k = ((u64)fkey(acc[i][j][r]) << 32) |
                        (u64)(0x1FFFu - (u32)gcol);   // smaller col wins ties
                if (k > b) { s = b; b = k; } else if (k > s) { s = k; }
            }
            #pragma unroll
            for (int off = 1; off < 16; off <<= 1) {
                u64 ob = __shfl_xor(b, off, 64);
                u64 os = __shfl_xor(s, off, 64);
                u64 nb = (b > ob) ? b : ob;
                u64 ns = (b > ob) ? ((ob > s) ? ob : s) : ((b > os) ? b : os);
                b = nb; s = ns;
            }
            if (m == 0) {
                ulonglong2 v; v.x = b; v.y = s;
                *(ulonglong2*)&topk[(size_t)grow * 256 + g * 2] = v;
            }
        }
    }
}

// ---------- scan top-2 keys, exact fp32 rescore of near-max, fused gather ----------
__global__ __launch_bounds__(256) void scan_kernel(
    const u64* __restrict__ topk,
    const float* __restrict__ x, const float* __restrict__ Wk,
    const float* __restrict__ WgT, float* __restrict__ out)
{
    __shared__ u64 wmax[4];
    __shared__ int cnt;
    __shared__ u64 candk[64];
    __shared__ float wpart[4];
    __shared__ int wincol;
    const int row = blockIdx.x;
    const int tid = threadIdx.x;
    if (tid == 0) cnt = 0;

    u64 key = topk[(size_t)row * 256 + tid];
    u64 mx = key;
    #pragma unroll
    for (int off = 1; off < 64; off <<= 1) {
        u64 o = __shfl_xor(mx, off, 64);
        if (o > mx) mx = o;
    }
    if ((tid & 63) == 0) wmax[tid >> 6] = mx;
    __syncthreads();                 // also orders cnt=0 before the atomics below
    u64 gmax = wmax[0];
    #pragma unroll
    for (int i = 1; i < 4; i++) if (wmax[i] > gmax) gmax = wmax[i];

    // screen window: bf16-input GEMM error << 1.0 (values are fp32 accumulators)
    const float thr = unfkey((u32)(gmax >> 32)) - 1.0f;
    const float myv = unfkey((u32)(key >> 32));
    if (myv >= thr) { int c = atomicAdd(&cnt, 1); if (c < 64) candk[c] = key; }
    __syncthreads();
    const int n = min(cnt, 64);

    int col;
    if (n == 1) {
        col = 0x1FFF - (int)(candk[0] & 0xFFFFu);
    } else {
        u64 best = 0ull;
        const float4* xr = (const float4*)(x + (size_t)row * IN);
        const float4 a0 = xr[tid * 2], a1 = xr[tid * 2 + 1];
        for (int c = 0; c < n; c++) {
            const int h = 0x1FFF - (int)(candk[c] & 0xFFFFu);
            const float4* wr = (const float4*)(Wk + (size_t)h * IN);
            float4 b0 = wr[tid * 2], b1 = wr[tid * 2 + 1];
            float p = a0.x * b0.x + a0.y * b0.y + a0.z * b0.z + a0.w * b0.w
                    + a1.x * b1.x + a1.y * b1.y + a1.z * b1.z + a1.w * b1.w;
            #pragma unroll
            for (int off = 1; off < 64; off <<= 1) p += __shfl_xor(p, off, 64);
            if ((tid & 63) == 0) wpart[tid >> 6] = p;
            __syncthreads();
            if (tid == 0) {
                float sv = wpart[0] + wpart[1] + wpart[2] + wpart[3];
                u64 k2 = ((u64)fkey(sv) << 32) | (u64)(0x1FFFu - (u32)h);
                if (k2 > best) best = k2;
            }
            __syncthreads();
        }
        if (tid == 0) wincol = 0x1FFF - (int)(best & 0xFFFFu);
        __syncthreads();
        col = wincol;
    }

    // fused gather: out[row, :] = WgT[col, :]
    const float* src = WgT + (size_t)col * NCLS;
    for (int c = tid; c < NCLS; c += 256)
        out[(size_t)row * NCLS + c] = src[c];
}

// ---------- round-1 fp32 fallback (used only if ws too small) ----------
__global__ void init_ws_kernel(u64* rowkey) {
    int i = blockIdx.x * blockDim.x + threadIdx.x;
    if (i < BATCH) rowkey[i] = 0ULL;
}

__global__ __launch_bounds__(256) void gemm_argmax_kernel(
    const float* __restrict__ x, const float* __restrict__ Wk,
    u64* __restrict__ rowkey)
{
    __shared__ __align__(16) float As[32 * 64];
    __shared__ __align__(16) float Bs[32 * 64];
    const int tid = threadIdx.x;
    const int bm = blockIdx.y * 64, bn = blockIdx.x * 64;
    const int tx = tid & 15, ty = tid >> 4;
    float acc[4][4];
    #pragma unroll
    for (int i = 0; i < 4; i++)
        #pragma unroll
        for (int j = 0; j < 4; j++) acc[i][j] = 0.f;
    const int r0 = tid >> 3, q0 = tid & 7;
    const int r1 = (tid + 256) >> 3, q1 = (tid + 256) & 7;
    const float* xA0 = &x[(size_t)(bm + r0) * IN + q0 * 4];
    const float* xA1 = &x[(size_t)(bm + r1) * IN + q1 * 4];
    const float* wB0 = &Wk[(size_t)(bn + r0) * IN + q0 * 4];
    const float* wB1 = &Wk[(size_t)(bn + r1) * IN + q1 * 4];
    for (int k0 = 0; k0 < IN; k0 += 32) {
        float4 a0 = *(const float4*)(xA0 + k0);
        float4 a1 = *(const float4*)(xA1 + k0);
        float4 b0 = *(const float4*)(wB0 + k0);
        float4 b1 = *(const float4*)(wB1 + k0);
        __syncthreads();
        As[(q0 * 4 + 0) * 64 + r0] = a0.x; As[(q0 * 4 + 1) * 64 + r0] = a0.y;
        As[(q0 * 4 + 2) * 64 + r0] = a0.z; As[(q0 * 4 + 3) * 64 + r0] = a0.w;
        As[(q1 * 4 + 0) * 64 + r1] = a1.x; As[(q1 * 4 + 1) * 64 + r1] = a1.y;
        As[(q1 * 4 + 2) * 64 + r1] = a1.z; As[(q1 * 4 + 3) * 64 + r1] = a1.w;
        Bs[(q0 * 4 + 0) * 64 + r0] = b0.x; Bs[(q0 * 4 + 1) * 64 + r0] = b0.y;
        Bs[(q0 * 4 + 2) * 64 + r0] = b0.z; Bs[(q0 * 4 + 3) * 64 + r0] = b0.w;
        Bs[(q1 * 4 + 0) * 64 + r1] = b1.x; Bs[(q1 * 4 + 1) * 64 + r1] = b1.y;
        Bs[(q1 * 4 + 2) * 64 + r1] = b1.z; Bs[(q1 * 4 + 3) * 64 + r1] = b1.w;
        __syncthreads();
        #pragma unroll
        for (int k = 0; k < 32; k++) {
            float4 av = *(const float4*)&As[k * 64 + ty * 4];
            float4 bv = *(const float4*)&Bs[k * 64 + tx * 4];
            acc[0][0] += av.x * bv.x; acc[0][1] += av.x * bv.y;
            acc[0][2] += av.x * bv.z; acc[0][3] += av.x * bv.w;
            acc[1][0] += av.y * bv.x; acc[1][1] += av.y * bv.y;
            acc[1][2] += av.y * bv.z; acc[1][3] += av.y * bv.w;
            acc[2][0] += av.z * bv.x; acc[2][1] += av.z * bv.y;
            acc[2][2] += av.z * bv.z; acc[2][3] += av.z * bv.w;
            acc[3][0] += av.w * bv.x; acc[3][1] += av.w * bv.y;
            acc[3][2] += av.w * bv.z; acc[3][3] += av.w * bv.w;
        }
    }
    #pragma unroll
    for (int i = 0; i < 4; i++) {
        const int row = bm + ty * 4 + i;
        u64 best = 0ULL;
        #pragma unroll
        for (int j = 0; j < 4; j++) {
            const int col = bn + tx * 4 + j;
            u64 p = ((u64)fkey(acc[i][j]) << 32) | (u64)(0x1FFFu - (unsigned)col);
            if (p > best) best = p;
        }
        #pragma unroll
        for (int off = 1; off < 16; off <<= 1) {
            u64 other = __shfl_xor(best, off, 64);
            if (other > best) best = other;
        }
        if (tx == 0) atomicMax(&rowkey[row], best);
    }
}

__global__ __launch_bounds__(256) void gather_kernel(
    const u64* __restrict__ rowkey, const float* __restrict__ Wg,
    float* __restrict__ out)
{
    const int b = blockIdx.y;
    const int c = blockIdx.x * 256 + threadIdx.x;
    if (c >= NCLS) return;
    const int col = 0x1FFF - (int)(rowkey[b] & 0xFFFFFFFFu);
    out[(size_t)b * NCLS + c] = Wg[(size_t)c * HID + col];
}

// ---------- launch ----------
extern "C" void kernel_launch(void* const* d_in, const int* in_sizes, int n_in,
                              void* d_out, int out_size, void* d_ws, size_t ws_size,
                              hipStream_t stream) {
    const float* x  = (const float*)d_in[0];
    const float* Wk = (const float*)d_in[1];
    const float* Wg = (const float*)d_in[2];
    float* out = (float*)d_out;
    char* ws = (char*)d_ws;

    if (ws_size >= TOTAL_FULL) {
        u64* topk  = (u64*)(ws + OFF_TOPK);
        u32* xb    = (u32*)(ws + OFF_XB);
        u32* wkb   = (u32*)(ws + OFF_WKB);
        float* WgT = (float*)(ws + OFF_WGT);

        hipLaunchKernelGGL(prep_kernel, dim3(2048), dim3(256), 0, stream,
                           x, Wk, xb, wkb);
        hipLaunchKernelGGL(transpose_wg_kernel, dim3(256, 32), dim3(256), 0, stream,
                           Wg, WgT);
        hipLaunchKernelGGL(mfma_gemm_kernel, dim3(HID / 128, BATCH / 128), dim3(256), 0, stream,
                           (const u16*)xb, (const u16*)wkb, topk);
        hipLaunchKernelGGL(scan_kernel, dim3(BATCH), dim3(256), 0, stream,
                           topk, x, Wk, WgT, out);
    } else {
        u64* rowkey = (u64*)(ws + OFF_ROWKEY);
        hipLaunchKernelGGL(init_ws_kernel, dim3(16), dim3(256), 0, stream, rowkey);
        hipLaunchKernelGGL(gemm_argmax_kernel, dim3(HID / 64, BATCH / 64), dim3(256), 0, stream,
                           x, Wk, rowkey);
        hipLaunchKernelGGL(gather_kernel, dim3(4, BATCH), dim3(256), 0, stream,
                           rowkey, Wg, out);
    }
}